// Round 3
// baseline (10268.366 us; speedup 1.0000x reference)
//
#include <hip/hip_runtime.h>

#define S_LEN 1024
#define B_SZ  64
#define D_IN  512
#define U_SZ  512
#define NWG_DIR 64       // producer slots per direction (= 64 WGs, 8 units each)
#define UNITS_PER_WG 8   // per direction
#define NT 2             // two 16-col MFMA n-tiles (cols = 4 gates x 8 units)
#define KSTEPS 32        // K = 1024 (x:512 + h:512) / 32

typedef __attribute__((ext_vector_type(8))) short short8;
typedef __attribute__((ext_vector_type(4))) float floatx4;

union HQ { unsigned long long q[2]; short8 s; };

__device__ __forceinline__ unsigned short f2bf(float f) {
  union { float f; unsigned u; } v; v.f = f;
  unsigned r = v.u + 0x7fffu + ((v.u >> 16) & 1u);   // RNE
  return (unsigned short)(r >> 16);
}
__device__ __forceinline__ float fsig(float x) {
  return __builtin_amdgcn_rcpf(1.0f + __expf(-x));
}
__device__ __forceinline__ float ftanh(float x) {
  return 1.0f - 2.0f * __builtin_amdgcn_rcpf(__expf(2.0f * x) + 1.0f);
}

// ---- transpose inputs [B,S,D] f32 -> [S,B,D] bf16 ----
__global__ void xprep_kernel(const float* __restrict__ x,
                             unsigned short* __restrict__ Axt) {
  int bs = blockIdx.x;                 // b*1024 + s
  int b = bs >> 10, s = bs & 1023;
  float4 v = ((const float4*)x)[(size_t)bs * 128 + threadIdx.x];
  ushort4 o;
  o.x = f2bf(v.x); o.y = f2bf(v.y); o.z = f2bf(v.z); o.w = f2bf(v.w);
  ((ushort4*)(Axt + ((size_t)s * B_SZ + b) * D_IN))[threadIdx.x] = o;
}

// ---- pack mask[B,S] (dtype auto-detected) into per-timestep 64-bit masks ----
__global__ void maskpack_kernel(const unsigned int* __restrict__ mraw,
                                unsigned long long* __restrict__ maskbits) {
  int t = blockIdx.x * blockDim.x + threadIdx.x;
  if (t >= S_LEN) return;
  unsigned d0 = mraw[0];               // mask[0][0..3] always true (len>=512)
  unsigned long long bits = 0;
  if (d0 == 1u) {                      // int32 layout
    const int* m = (const int*)mraw;
    for (int b = 0; b < B_SZ; ++b) if (m[b * S_LEN + t]) bits |= 1ull << b;
  } else if (d0 == 0x3f800000u) {      // float layout
    const float* m = (const float*)mraw;
    for (int b = 0; b < B_SZ; ++b) if (m[b * S_LEN + t] != 0.f) bits |= 1ull << b;
  } else {                             // byte/bool layout
    const unsigned char* m = (const unsigned char*)mraw;
    for (int b = 0; b < B_SZ; ++b) if (m[b * S_LEN + t]) bits |= 1ull << b;
  }
  maskbits[t] = bits;
}

// ---- persistent bidirectional LSTM scan, BOTH directions per WG ----
// 64 WGs. Each WG owns units [wg*8, wg*8+8) for BOTH directions, all 64
// batches. The two independent scans are interleaved so each direction's
// compute hides the other's sync round-trips (store drain / flag propagate /
// h-load RTT). Cross-WG h exchange via relaxed AGENT-scope atomics
// (write-through, coherence-point reads). Distributed per-WG flags.
// Deadlock-freedom: iteration t's first poll needs all WGs past the MID of
// t-1 (flags0=t), second poll needs all past the END of t-1 (flags1=t);
// monotone induction over t. All __syncthreads() are block-uniform.
// h layout per dir: [buf][wg_group=u/8][b][u%8] bf16 (16B per A-frag).
__global__ __launch_bounds__(256, 1) void lstm_scan_kernel(
    const unsigned short* __restrict__ Axt,
    const float* __restrict__ kernel_f, const float* __restrict__ rkernel_f,
    const float* __restrict__ bias_f,
    const float* __restrict__ kernel_b, const float* __restrict__ rkernel_b,
    const float* __restrict__ bias_b,
    const unsigned long long* __restrict__ maskbits,
    unsigned short* __restrict__ hbuf,   // [2 dir][2 buf][64][64][8] bf16
    unsigned int* __restrict__ ctrs,     // [2 dir][64] flags
    float* __restrict__ out) {
  __shared__ alignas(16) short lds_b[2][NT * KSTEPS * 64 * 8];   // 128 KiB

  const int tid  = threadIdx.x;
  const int lane = tid & 63;
  const int wv   = tid >> 6;           // wave = M-tile (16 batches)
  const int wg   = blockIdx.x;         // 0..63
  const int u0   = wg * UNITS_PER_WG;

  // Fill LDS B-fragments for both directions: element (nt,ks,lane,j) =
  // Wcat[k][col], k = ks*32 + (lane>>4)*8 + j (rows 0..511 = W, 512..1023 = R),
  // col = gate*512 + u0 + du, gate = nt*2 + ((lane&15)>>3), du = lane&7.
  for (int d = 0; d < 2; ++d) {
    const float* Wk = d ? kernel_b  : kernel_f;
    const float* Rk = d ? rkernel_b : rkernel_f;
    for (int item = tid; item < NT * KSTEPS * 64; item += 256) {
      int nt = item >> 11;
      int rem = item & 2047;
      int ks = rem >> 6;
      int ln = rem & 63;
      int kbase = ks * 32 + ((ln >> 4) << 3);
      int col16 = ln & 15;
      int gate = nt * 2 + (col16 >> 3);
      int cg = gate * U_SZ + u0 + (col16 & 7);
      short8 v;
#pragma unroll
      for (int j = 0; j < 8; ++j) {
        int k = kbase + j;
        float f = (k < D_IN) ? Wk[(size_t)k * 2048 + cg]
                             : Rk[(size_t)(k - D_IN) * 2048 + cg];
        v[j] = (short)f2bf(f);
      }
      *(short8*)(&lds_b[d][item * 8]) = v;
    }
  }
  __syncthreads();

  const int du = lane & 7;
  const int u  = u0 + du;
  float bz0[4], bz1[4];
#pragma unroll
  for (int g = 0; g < 4; ++g) {
    bz0[g] = bias_f[g * U_SZ + u];
    bz1[g] = bias_b[g * U_SZ + u];
  }

  float c0[4] = {0.f, 0.f, 0.f, 0.f}, h0s[4] = {0.f, 0.f, 0.f, 0.f};
  float c1[4] = {0.f, 0.f, 0.f, 0.f}, h1s[4] = {0.f, 0.f, 0.f, 0.f};

  unsigned short* hb0 = hbuf;                            // dir0 slab
  unsigned short* hb1 = hbuf + (size_t)2 * B_SZ * U_SZ;  // dir1 slab
  unsigned int* flags0 = ctrs;
  unsigned int* flags1 = ctrs + 64;

  const int mrow  = lane & 15;         // A-row within M-tile
  const int kq    = (lane >> 4) << 3;  // quad k-offset
  const bool active = (lane & 8) == 0; // lanes holding i/g (partner holds f/o)
  const int brow0 = wv * 16 + ((lane >> 4) << 2);
  const int brow  = wv * 16 + mrow;

  for (int t = 0; t < S_LEN; ++t) {
    const int sx0 = t;
    const int sx1 = S_LEN - 1 - t;
    const unsigned long long mb0 = maskbits[sx0];
    const unsigned long long mb1 = maskbits[sx1];

    // ---- preload dir0 x A-frags (independent of sync, issued pre-poll) ----
    const unsigned short* xs0 =
        Axt + (size_t)sx0 * B_SZ * D_IN + (size_t)brow * D_IN + kq;
    short8 xa[16];
#pragma unroll
    for (int ks = 0; ks < 16; ++ks) xa[ks] = *(const short8*)(xs0 + ks * 32);

    // ---- wait for dir0 step t-1 (all WGs) ----
    if (t > 0) {
      if (wv == 0) {
        unsigned target = (unsigned)t;
        while (true) {
          unsigned v = __hip_atomic_load(&flags0[lane], __ATOMIC_RELAXED,
                                         __HIP_MEMORY_SCOPE_AGENT);
          if (__ballot(v >= target) == ~0ull) break;
          __builtin_amdgcn_s_sleep(1);
        }
      }
      __syncthreads();
    }

    // ---- dir0: issue h loads; x@W MFMAs (register A) hide their RTT ----
    const unsigned long long* hr0 = (const unsigned long long*)(
        hb0 + (size_t)((t + 1) & 1) * B_SZ * U_SZ);
    HQ hq[16];
#pragma unroll
    for (int ks = 0; ks < 16; ++ks) {
      int wgp = ks * 4 + (lane >> 4);
      const unsigned long long* p = hr0 + (size_t)(wgp * 64 + brow) * 2;
      hq[ks].q[0] = __hip_atomic_load(p, __ATOMIC_RELAXED,
                                      __HIP_MEMORY_SCOPE_AGENT);
      hq[ks].q[1] = __hip_atomic_load(p + 1, __ATOMIC_RELAXED,
                                      __HIP_MEMORY_SCOPE_AGENT);
    }

    floatx4 acc0 = {0.f, 0.f, 0.f, 0.f};
    floatx4 acc1 = {0.f, 0.f, 0.f, 0.f};
#pragma unroll
    for (int ks = 0; ks < 16; ++ks) {
      short8 b0 = *(const short8*)(&lds_b[0][((0 * KSTEPS + ks) * 64 + lane) * 8]);
      short8 b1 = *(const short8*)(&lds_b[0][((1 * KSTEPS + ks) * 64 + lane) * 8]);
      acc0 = __builtin_amdgcn_mfma_f32_16x16x32_bf16(xa[ks], b0, acc0, 0, 0, 0);
      acc1 = __builtin_amdgcn_mfma_f32_16x16x32_bf16(xa[ks], b1, acc1, 0, 0, 0);
    }
#pragma unroll
    for (int ks = 0; ks < 16; ++ks) {
      short8 b0 = *(const short8*)(&lds_b[0][((0 * KSTEPS + 16 + ks) * 64 + lane) * 8]);
      short8 b1 = *(const short8*)(&lds_b[0][((1 * KSTEPS + 16 + ks) * 64 + lane) * 8]);
      acc0 = __builtin_amdgcn_mfma_f32_16x16x32_bf16(hq[ks].s, b0, acc0, 0, 0, 0);
      acc1 = __builtin_amdgcn_mfma_f32_16x16x32_bf16(hq[ks].s, b1, acc1, 0, 0, 0);
    }

    // gates dir0
#pragma unroll
    for (int r = 0; r < 4; ++r) {
      float iv = acc0[r];
      float gv = acc1[r];
      float fv = __shfl_xor(iv, 8, 64);
      float ov = __shfl_xor(gv, 8, 64);
      float zi = iv + bz0[0], zf = fv + bz0[1], zg = gv + bz0[2], zo = ov + bz0[3];
      float cn = fsig(zf) * c0[r] + fsig(zi) * ftanh(zg);
      float hn = fsig(zo) * ftanh(cn);
      int b = brow0 + r;
      bool m = (mb0 >> b) & 1ull;
      c0[r] = m ? cn : c0[r];
      h0s[r] = m ? hn : h0s[r];
    }

    // publish dir0 h
    {
      unsigned short* hw = hb0 + (size_t)(t & 1) * B_SZ * U_SZ +
                           (size_t)wg * 512;
#pragma unroll
      for (int r = 0; r < 4; ++r) {
        unsigned hv = f2bf(h0s[r]);
        unsigned pv = (unsigned)__shfl_xor((int)hv, 1, 64);
        unsigned packed = (hv & 0xffffu) | (pv << 16);
        if (active && !(lane & 1)) {
          int b = brow0 + r;
          __hip_atomic_store((unsigned*)(hw + b * 8 + du), packed,
                             __ATOMIC_RELAXED, __HIP_MEMORY_SCOPE_AGENT);
        }
      }
    }

    // ---- preload dir1 x A-frags (independent; drains alongside publish0) ----
    const unsigned short* xs1 =
        Axt + (size_t)sx1 * B_SZ * D_IN + (size_t)brow * D_IN + kq;
#pragma unroll
    for (int ks = 0; ks < 16; ++ks) xa[ks] = *(const short8*)(xs1 + ks * 32);

    // ---- wave0 polls dir1 while all waves drain publish0; then flag0 ----
    if (t > 0 && wv == 0) {
      unsigned target = (unsigned)t;
      while (true) {
        unsigned v = __hip_atomic_load(&flags1[lane], __ATOMIC_RELAXED,
                                       __HIP_MEMORY_SCOPE_AGENT);
        if (__ballot(v >= target) == ~0ull) break;
        __builtin_amdgcn_s_sleep(1);
      }
    }
    asm volatile("s_waitcnt vmcnt(0)" ::: "memory");
    __syncthreads();
    if (tid == 0)
      __hip_atomic_store(&flags0[wg], (unsigned)(t + 1), __ATOMIC_RELAXED,
                         __HIP_MEMORY_SCOPE_AGENT);

    // ---- dir1: issue h loads; x@W MFMAs (register A) hide their RTT ----
    const unsigned long long* hr1 = (const unsigned long long*)(
        hb1 + (size_t)((t + 1) & 1) * B_SZ * U_SZ);
#pragma unroll
    for (int ks = 0; ks < 16; ++ks) {
      int wgp = ks * 4 + (lane >> 4);
      const unsigned long long* p = hr1 + (size_t)(wgp * 64 + brow) * 2;
      hq[ks].q[0] = __hip_atomic_load(p, __ATOMIC_RELAXED,
                                      __HIP_MEMORY_SCOPE_AGENT);
      hq[ks].q[1] = __hip_atomic_load(p + 1, __ATOMIC_RELAXED,
                                      __HIP_MEMORY_SCOPE_AGENT);
    }

    floatx4 acc2 = {0.f, 0.f, 0.f, 0.f};
    floatx4 acc3 = {0.f, 0.f, 0.f, 0.f};
#pragma unroll
    for (int ks = 0; ks < 16; ++ks) {
      short8 b0 = *(const short8*)(&lds_b[1][((0 * KSTEPS + ks) * 64 + lane) * 8]);
      short8 b1 = *(const short8*)(&lds_b[1][((1 * KSTEPS + ks) * 64 + lane) * 8]);
      acc2 = __builtin_amdgcn_mfma_f32_16x16x32_bf16(xa[ks], b0, acc2, 0, 0, 0);
      acc3 = __builtin_amdgcn_mfma_f32_16x16x32_bf16(xa[ks], b1, acc3, 0, 0, 0);
    }
#pragma unroll
    for (int ks = 0; ks < 16; ++ks) {
      short8 b0 = *(const short8*)(&lds_b[1][((0 * KSTEPS + 16 + ks) * 64 + lane) * 8]);
      short8 b1 = *(const short8*)(&lds_b[1][((1 * KSTEPS + 16 + ks) * 64 + lane) * 8]);
      acc2 = __builtin_amdgcn_mfma_f32_16x16x32_bf16(hq[ks].s, b0, acc2, 0, 0, 0);
      acc3 = __builtin_amdgcn_mfma_f32_16x16x32_bf16(hq[ks].s, b1, acc3, 0, 0, 0);
    }

    // gates dir1
#pragma unroll
    for (int r = 0; r < 4; ++r) {
      float iv = acc2[r];
      float gv = acc3[r];
      float fv = __shfl_xor(iv, 8, 64);
      float ov = __shfl_xor(gv, 8, 64);
      float zi = iv + bz1[0], zf = fv + bz1[1], zg = gv + bz1[2], zo = ov + bz1[3];
      float cn = fsig(zf) * c1[r] + fsig(zi) * ftanh(zg);
      float hn = fsig(zo) * ftanh(cn);
      int b = brow0 + r;
      bool m = (mb1 >> b) & 1ull;
      c1[r] = m ? cn : c1[r];
      h1s[r] = m ? hn : h1s[r];
    }

    // publish dir1 h
    {
      unsigned short* hw = hb1 + (size_t)(t & 1) * B_SZ * U_SZ +
                           (size_t)wg * 512;
#pragma unroll
      for (int r = 0; r < 4; ++r) {
        unsigned hv = f2bf(h1s[r]);
        unsigned pv = (unsigned)__shfl_xor((int)hv, 1, 64);
        unsigned packed = (hv & 0xffffu) | (pv << 16);
        if (active && !(lane & 1)) {
          int b = brow0 + r;
          __hip_atomic_store((unsigned*)(hw + b * 8 + du), packed,
                             __ATOMIC_RELAXED, __HIP_MEMORY_SCOPE_AGENT);
        }
      }
    }

    asm volatile("s_waitcnt vmcnt(0)" ::: "memory");
    __syncthreads();
    if (tid == 0)
      __hip_atomic_store(&flags1[wg], (unsigned)(t + 1), __ATOMIC_RELAXED,
                         __HIP_MEMORY_SCOPE_AGENT);

    // ---- output writes AFTER signals — off the inter-WG critical path ----
    if (active) {
#pragma unroll
      for (int r = 0; r < 4; ++r) {
        int b = brow0 + r;
        __builtin_nontemporal_store(
            h0s[r], out + ((size_t)b * S_LEN + sx0) * 1024 + u);
        __builtin_nontemporal_store(
            h1s[r], out + ((size_t)b * S_LEN + sx1) * 1024 + U_SZ + u);
      }
      if (t == S_LEN - 1) {            // final h, c (post-mask carries)
        float* fin0 = out + (size_t)B_SZ * S_LEN * 1024;
        float* fin1 = fin0 + (size_t)2 * B_SZ * U_SZ;
#pragma unroll
        for (int r = 0; r < 4; ++r) {
          int b = brow0 + r;
          fin0[b * U_SZ + u] = h0s[r];
          fin0[B_SZ * U_SZ + b * U_SZ + u] = c0[r];
          fin1[b * U_SZ + u] = h1s[r];
          fin1[B_SZ * U_SZ + b * U_SZ + u] = c1[r];
        }
      }
    }
  }
}

extern "C" void kernel_launch(void* const* d_in, const int* in_sizes, int n_in,
                              void* d_out, int out_size, void* d_ws, size_t ws_size,
                              hipStream_t stream) {
  const float* inputs    = (const float*)d_in[0];
  const void*  mask      = d_in[1];
  const float* kernel_f  = (const float*)d_in[2];
  const float* rkernel_f = (const float*)d_in[3];
  const float* bias_f    = (const float*)d_in[4];
  const float* rkernel_b_dummy = nullptr; (void)rkernel_b_dummy;
  const float* kernel_b  = (const float*)d_in[5];
  const float* rkernel_b = (const float*)d_in[6];
  const float* bias_b    = (const float*)d_in[7];
  float* out = (float*)d_out;

  char* ws = (char*)d_ws;
  unsigned short* Axt = (unsigned short*)ws;              // 67,108,864 B
  size_t off = (size_t)S_LEN * B_SZ * D_IN * 2;
  unsigned short* hbuf = (unsigned short*)(ws + off);     // 262,144 B
  unsigned int* ctrs = (unsigned int*)(ws + off + 262144);          // 512 B
  unsigned long long* maskbits =
      (unsigned long long*)(ws + off + 262144 + 512);     // 8,192 B

  hipMemsetAsync(hbuf, 0, 262144 + 512, stream);          // h state + flags
  maskpack_kernel<<<4, 256, 0, stream>>>((const unsigned int*)mask, maskbits);
  xprep_kernel<<<S_LEN * B_SZ, 128, 0, stream>>>(inputs, Axt);
  lstm_scan_kernel<<<64, 256, 0, stream>>>(Axt, kernel_f, rkernel_f, bias_f,
                                           kernel_b, rkernel_b, bias_b,
                                           maskbits, hbuf, ctrs, out);
}

// Round 5
// 9798.827 us; speedup vs baseline: 1.0479x; 1.0479x over previous
//
#include <hip/hip_runtime.h>

#define S_LEN 1024
#define B_SZ  64
#define D_IN  512
#define U_SZ  512
#define NWG_DIR 64       // workgroups per direction
#define UNITS_PER_WG 8   // 512 / 64
#define NT 2             // two 16-col MFMA n-tiles (cols = 4 gates x 8 units)
#define KSTEPS 32        // K = 1024 (x:512 + h:512) / 32
#define HB_DW 32768      // dwords per h buffer per dir: 64 wgp * 64 b * 8 du
#define SPIN_CAP (1 << 17)  // watchdog: bounded spin -> visible failure, not hang

typedef __attribute__((ext_vector_type(8))) short short8;
typedef __attribute__((ext_vector_type(4))) float floatx4;

union HF { unsigned d[4]; short8 s; };

__device__ __forceinline__ unsigned short f2bf(float f) {
  union { float f; unsigned u; } v; v.f = f;
  unsigned r = v.u + 0x7fffu + ((v.u >> 16) & 1u);   // RNE
  return (unsigned short)(r >> 16);
}
__device__ __forceinline__ float fsig(float x) {
  return __builtin_amdgcn_rcpf(1.0f + __expf(-x));
}
__device__ __forceinline__ float ftanh(float x) {
  return 1.0f - 2.0f * __builtin_amdgcn_rcpf(__expf(2.0f * x) + 1.0f);
}

// ---- transpose inputs [B,S,D] f32 -> [S,B,D] bf16 ----
__global__ void xprep_kernel(const float* __restrict__ x,
                             unsigned short* __restrict__ Axt) {
  int bs = blockIdx.x;                 // b*1024 + s
  int b = bs >> 10, s = bs & 1023;
  float4 v = ((const float4*)x)[(size_t)bs * 128 + threadIdx.x];
  ushort4 o;
  o.x = f2bf(v.x); o.y = f2bf(v.y); o.z = f2bf(v.z); o.w = f2bf(v.w);
  ((ushort4*)(Axt + ((size_t)s * B_SZ + b) * D_IN))[threadIdx.x] = o;
}

// ---- pack mask[B,S] (dtype auto-detected) into per-timestep 64-bit masks ----
__global__ void maskpack_kernel(const unsigned int* __restrict__ mraw,
                                unsigned long long* __restrict__ maskbits) {
  int t = blockIdx.x * blockDim.x + threadIdx.x;
  if (t >= S_LEN) return;
  unsigned d0 = mraw[0];               // mask[0][0..3] always true (len>=512)
  unsigned long long bits = 0;
  if (d0 == 1u) {                      // int32 layout
    const int* m = (const int*)mraw;
    for (int b = 0; b < B_SZ; ++b) if (m[b * S_LEN + t]) bits |= 1ull << b;
  } else if (d0 == 0x3f800000u) {      // float layout
    const float* m = (const float*)mraw;
    for (int b = 0; b < B_SZ; ++b) if (m[b * S_LEN + t] != 0.f) bits |= 1ull << b;
  } else {                             // byte/bool layout
    const unsigned char* m = (const unsigned char*)mraw;
    for (int b = 0; b < B_SZ; ++b) if (m[b * S_LEN + t]) bits |= 1ull << b;
  }
  maskbits[t] = bits;
}

// ---- persistent bidirectional LSTM scan, SELF-VERIFYING TAGGED h ----
// 128 WGs: [0,64) forward, [64,128) backward. Each WG owns 8 units for all
// 64 batches. h exchange: every h dword = (tag<<16)|bf16(h), tag = step+1.
// Consumers load h granules directly and verify tags in-register; retry on
// stale. NO flags, NO vmcnt drain, NO __syncthreads in the scan loop —
// producer proceeds immediately after issuing tagged stores.
// Safety/liveness: per wave-class (rows wv*16..wv*16+15) the 64 WGs form an
// independent ring; a tag-(t+2) write into buffer (t+1)&1 is gated on
// verifying tag t+1 from ALL wgp columns of that row class, and each WG's
// tag-(t+1) store is issued only after its step-t verify loop broke (reads
// complete). So an exact-match consumer can never see t+2 while waiting for
// t. Tag 0 == memset == h(-1)=0. Bounded spin (SPIN_CAP) converts any
// residual liveness bug into a visible correctness failure instead of a hang.
// h layout per dir per buf: dword[(wgp*64 + b)*8 + du] (32B granule/b,wgp).
__global__ __launch_bounds__(256, 1) void lstm_scan_kernel(
    const unsigned short* __restrict__ Axt,
    const float* __restrict__ kernel_f, const float* __restrict__ rkernel_f,
    const float* __restrict__ bias_f,
    const float* __restrict__ kernel_b, const float* __restrict__ rkernel_b,
    const float* __restrict__ bias_b,
    const unsigned long long* __restrict__ maskbits,
    unsigned* __restrict__ hseq,         // [2 dir][2 buf][HB_DW] tagged dwords
    float* __restrict__ out) {
  __shared__ alignas(16) short lds_b[NT * KSTEPS * 64 * 8];   // 64 KiB

  const int tid  = threadIdx.x;
  const int lane = tid & 63;
  const int wv   = tid >> 6;           // wave = M-tile (16 batches)
  const int dir  = blockIdx.x >> 6;
  const int wg   = blockIdx.x & 63;
  const int u0   = wg * UNITS_PER_WG;

  const float* Wk   = dir ? kernel_b  : kernel_f;
  const float* Rk   = dir ? rkernel_b : rkernel_f;
  const float* bias = dir ? bias_b    : bias_f;

  // Fill LDS B-fragments: element (nt,ks,lane,j) = Wcat[k][col],
  // k = ks*32 + (lane>>4)*8 + j  (rows 0..511 = W, 512..1023 = R),
  // col = gate*512 + u0 + du,  gate = nt*2 + ((lane&15)>>3), du = lane&7.
  for (int item = tid; item < NT * KSTEPS * 64; item += 256) {
    int nt = item >> 11;
    int rem = item & 2047;
    int ks = rem >> 6;
    int ln = rem & 63;
    int kbase = ks * 32 + ((ln >> 4) << 3);
    int col16 = ln & 15;
    int gate = nt * 2 + (col16 >> 3);
    int cg = gate * U_SZ + u0 + (col16 & 7);
    short8 v;
#pragma unroll
    for (int j = 0; j < 8; ++j) {
      int k = kbase + j;
      float f = (k < D_IN) ? Wk[(size_t)k * 2048 + cg]
                           : Rk[(size_t)(k - D_IN) * 2048 + cg];
      v[j] = (short)f2bf(f);
    }
    *(short8*)(&lds_b[item * 8]) = v;
  }
  __syncthreads();                     // last barrier: LDS weights ready

  const int du = lane & 7;
  const int u  = u0 + du;
  float bz[4];
#pragma unroll
  for (int g = 0; g < 4; ++g) bz[g] = bias[g * U_SZ + u];

  float c_st[4] = {0.f, 0.f, 0.f, 0.f};
  float h_st[4] = {0.f, 0.f, 0.f, 0.f};

  unsigned* hb = hseq + (size_t)dir * 2 * HB_DW;

  const int mrow  = lane & 15;         // A-row within M-tile
  const int kq    = (lane >> 4) << 3;  // quad k-offset
  const bool active = (lane & 8) == 0; // lanes holding i/g (partner holds f/o)
  const int brow0 = wv * 16 + ((lane >> 4) << 2);
  const int brow  = wv * 16 + mrow;

  for (int t = 0; t < S_LEN; ++t) {
    const int sx = dir ? (S_LEN - 1 - t) : t;
    const unsigned short* xs =
        Axt + (size_t)sx * B_SZ * D_IN + (size_t)brow * D_IN + kq;
    floatx4 acc0 = {0.f, 0.f, 0.f, 0.f};
    floatx4 acc1 = {0.f, 0.f, 0.f, 0.f};

    // x @ W half — independent of h; overlaps other WGs' h-store landing
#pragma unroll
    for (int ks = 0; ks < 16; ++ks) {
      short8 a  = *(const short8*)(xs + ks * 32);
      short8 b0 = *(const short8*)(&lds_b[((0 * KSTEPS + ks) * 64 + lane) * 8]);
      short8 b1 = *(const short8*)(&lds_b[((1 * KSTEPS + ks) * 64 + lane) * 8]);
      acc0 = __builtin_amdgcn_mfma_f32_16x16x32_bf16(a, b0, acc0, 0, 0, 0);
      acc1 = __builtin_amdgcn_mfma_f32_16x16x32_bf16(a, b1, acc1, 0, 0, 0);
    }

    const unsigned long long mb = maskbits[sx];

    // ---- consume h(t-1): load tagged granules + in-register verify ----
    const unsigned long long* hr = (const unsigned long long*)(
        hb + (size_t)((t + 1) & 1) * HB_DW);
    const unsigned long long expp =
        ((unsigned long long)(unsigned)t << 48) |
        ((unsigned long long)(unsigned)t << 16);
    unsigned long long hq[16][4];
    int spins = 0;
    while (true) {
      unsigned long long bad = 0;
#pragma unroll
      for (int ks = 0; ks < 16; ++ks) {
        int wgp = ks * 4 + (lane >> 4);
        const unsigned long long* p = hr + (size_t)(wgp * 64 + brow) * 4;
#pragma unroll
        for (int j = 0; j < 4; ++j)
          hq[ks][j] = __hip_atomic_load(p + j, __ATOMIC_RELAXED,
                                        __HIP_MEMORY_SCOPE_AGENT);
      }
#pragma unroll
      for (int ks = 0; ks < 16; ++ks)
#pragma unroll
        for (int j = 0; j < 4; ++j)
          bad |= (hq[ks][j] ^ expp) & 0xFFFF0000FFFF0000ull;
      if (__ballot(bad == 0) == ~0ull) break;   // whole wave fresh
      if (++spins > SPIN_CAP) break;            // watchdog: fail visibly
      __builtin_amdgcn_s_sleep(2);
    }

    // ---- h @ R half: strip tags (1 v_perm per ull) and MFMA ----
#pragma unroll
    for (int ks = 0; ks < 16; ++ks) {
      HF hf;
#pragma unroll
      for (int j = 0; j < 4; ++j)
        hf.d[j] = __builtin_amdgcn_perm((unsigned)(hq[ks][j] >> 32),
                                        (unsigned)hq[ks][j], 0x05040100);
      short8 b0 = *(const short8*)(&lds_b[((0 * KSTEPS + 16 + ks) * 64 + lane) * 8]);
      short8 b1 = *(const short8*)(&lds_b[((1 * KSTEPS + 16 + ks) * 64 + lane) * 8]);
      acc0 = __builtin_amdgcn_mfma_f32_16x16x32_bf16(hf.s, b0, acc0, 0, 0, 0);
      acc1 = __builtin_amdgcn_mfma_f32_16x16x32_bf16(hf.s, b1, acc1, 0, 0, 0);
    }

    // gates: lane holds i (acc0) and g (acc1); partner lane^8 holds f and o
#pragma unroll
    for (int r = 0; r < 4; ++r) {
      float iv = acc0[r];
      float gv = acc1[r];
      float fv = __shfl_xor(iv, 8, 64);
      float ov = __shfl_xor(gv, 8, 64);
      float zi = iv + bz[0], zf = fv + bz[1], zg = gv + bz[2], zo = ov + bz[3];
      float cn = fsig(zf) * c_st[r] + fsig(zi) * ftanh(zg);
      float hn = fsig(zo) * ftanh(cn);
      int b = brow0 + r;
      bool m = (mb >> b) & 1ull;
      c_st[r] = m ? cn : c_st[r];
      h_st[r] = m ? hn : h_st[r];
    }

    // ---- produce h(t): tagged dword stores; NO drain, NO flag, NO barrier
    {
      unsigned* hw = hb + (size_t)(t & 1) * HB_DW;
      const unsigned tagv = (unsigned)(t + 1) << 16;
      if (active) {
#pragma unroll
        for (int r = 0; r < 4; ++r) {
          int b = brow0 + r;
          __hip_atomic_store(&hw[(size_t)(wg * 64 + b) * 8 + du],
                             tagv | (unsigned)f2bf(h_st[r]),
                             __ATOMIC_RELAXED, __HIP_MEMORY_SCOPE_AGENT);
        }
      }
    }

    // output writes — off the inter-WG critical path
    if (active) {
#pragma unroll
      for (int r = 0; r < 4; ++r) {
        int b = brow0 + r;
        __builtin_nontemporal_store(
            h_st[r], out + ((size_t)b * S_LEN + sx) * 1024 + dir * U_SZ + u);
      }
      if (t == S_LEN - 1) {            // final h, c (post-mask carries)
        float* fin = out + (size_t)B_SZ * S_LEN * 1024 +
                     (size_t)dir * 2 * B_SZ * U_SZ;
#pragma unroll
        for (int r = 0; r < 4; ++r) {
          int b = brow0 + r;
          fin[b * U_SZ + u] = h_st[r];
          fin[B_SZ * U_SZ + b * U_SZ + u] = c_st[r];
        }
      }
    }
  }
}

extern "C" void kernel_launch(void* const* d_in, const int* in_sizes, int n_in,
                              void* d_out, int out_size, void* d_ws, size_t ws_size,
                              hipStream_t stream) {
  const float* inputs    = (const float*)d_in[0];
  const void*  mask      = d_in[1];
  const float* kernel_f  = (const float*)d_in[2];
  const float* rkernel_f = (const float*)d_in[3];
  const float* bias_f    = (const float*)d_in[4];
  const float* kernel_b  = (const float*)d_in[5];
  const float* rkernel_b = (const float*)d_in[6];
  const float* bias_b    = (const float*)d_in[7];
  float* out = (float*)d_out;

  char* ws = (char*)d_ws;
  unsigned short* Axt = (unsigned short*)ws;              // 67,108,864 B
  size_t off = (size_t)S_LEN * B_SZ * D_IN * 2;
  unsigned* hseq = (unsigned*)(ws + off);                 // 524,288 B tagged h
  unsigned long long* maskbits =
      (unsigned long long*)(ws + off + 524288);           // 8,192 B

  hipMemsetAsync(hseq, 0, 524288, stream);                // tags=0 == h(-1)=0
  maskpack_kernel<<<4, 256, 0, stream>>>((const unsigned int*)mask, maskbits);
  xprep_kernel<<<S_LEN * B_SZ, 128, 0, stream>>>(inputs, Axt);
  lstm_scan_kernel<<<128, 256, 0, stream>>>(Axt, kernel_f, rkernel_f, bias_f,
                                            kernel_b, rkernel_b, bias_b,
                                            maskbits, hseq, out);
}

// Round 6
// 4968.411 us; speedup vs baseline: 2.0667x; 1.9722x over previous
//
#include <hip/hip_runtime.h>

#define S_LEN 1024
#define B_SZ  64
#define D_IN  512
#define U_SZ  512
#define SPIN_CAP (1 << 20)   // watchdog: visible failure instead of hang

typedef __attribute__((ext_vector_type(8))) short short8;
typedef __attribute__((ext_vector_type(4))) float floatx4;
typedef __attribute__((ext_vector_type(4))) unsigned uintx4;

union HU { uintx4 u; short8 s; };

__device__ __forceinline__ unsigned short f2bf(float f) {
  union { float f; unsigned u; } v; v.f = f;
  unsigned r = v.u + 0x7fffu + ((v.u >> 16) & 1u);   // RNE
  return (unsigned short)(r >> 16);
}
__device__ __forceinline__ float fsig(float x) {
  return __builtin_amdgcn_rcpf(1.0f + __expf(-x));
}
__device__ __forceinline__ float ftanh(float x) {
  return 1.0f - 2.0f * __builtin_amdgcn_rcpf(__expf(2.0f * x) + 1.0f);
}

// ---- transpose inputs [B,S,D] f32 -> [S,B,D] bf16 ----
__global__ void xprep_kernel(const float* __restrict__ x,
                             unsigned short* __restrict__ Axt) {
  int bs = blockIdx.x;                 // b*1024 + s
  int b = bs >> 10, s = bs & 1023;
  float4 v = ((const float4*)x)[(size_t)bs * 128 + threadIdx.x];
  ushort4 o;
  o.x = f2bf(v.x); o.y = f2bf(v.y); o.z = f2bf(v.z); o.w = f2bf(v.w);
  ((ushort4*)(Axt + ((size_t)s * B_SZ + b) * D_IN))[threadIdx.x] = o;
}

// ---- pack mask[B,S] (dtype auto-detected) into per-timestep 64-bit masks ----
__global__ void maskpack_kernel(const unsigned int* __restrict__ mraw,
                                unsigned long long* __restrict__ maskbits) {
  int t = blockIdx.x * blockDim.x + threadIdx.x;
  if (t >= S_LEN) return;
  unsigned d0 = mraw[0];
  unsigned long long bits = 0;
  if (d0 == 1u) {
    const int* m = (const int*)mraw;
    for (int b = 0; b < B_SZ; ++b) if (m[b * S_LEN + t]) bits |= 1ull << b;
  } else if (d0 == 0x3f800000u) {
    const float* m = (const float*)mraw;
    for (int b = 0; b < B_SZ; ++b) if (m[b * S_LEN + t] != 0.f) bits |= 1ull << b;
  } else {
    const unsigned char* m = (const unsigned char*)mraw;
    for (int b = 0; b < B_SZ; ++b) if (m[b * S_LEN + t]) bits |= 1ull << b;
  }
  maskbits[t] = bits;
}

// ---- weight prep: Wt[dir][c=2048][k=1024] bf16 (transposed Wcat) ----
// Wcat rows 0..511 = kernel, 512..1023 = rkernel; col c = gate*512 + unit.
__global__ void wprep_kernel(const float* __restrict__ kf,
                             const float* __restrict__ rf,
                             const float* __restrict__ kb,
                             const float* __restrict__ rb,
                             unsigned short* __restrict__ Wt) {
  int item = blockIdx.x * 256 + threadIdx.x;   // 2^20 items
  int c   = item & 2047;
  int kc  = (item >> 11) & 255;
  int dir = item >> 19;
  const float* K = dir ? kb : kf;
  const float* R = dir ? rb : rf;
  int k0 = kc * 4;
  unsigned long long pk = 0;
#pragma unroll
  for (int i = 0; i < 4; ++i) {
    int k = k0 + i;
    float f = (k < D_IN) ? K[(size_t)k * 2048 + c]
                         : R[(size_t)(k - D_IN) * 2048 + c];
    pk |= (unsigned long long)f2bf(f) << (16 * i);
  }
  *(unsigned long long*)(Wt + ((size_t)dir * 2048 + c) * 1024 + k0) = pk;
}

#define HLOAD(k, boff) \
  asm volatile("global_load_dwordx4 %0, %1, off offset:" #boff " sc0" \
               : "=v"(hq[k].u) : "v"(hr))

// ---- persistent bidirectional LSTM scan, XCD-LOCAL rings ----
// 256 WGs @ 1 WG/CU (128 KiB LDS forces it) -> exactly 32 WGs per XCD.
// Role: xcd = s_getreg(HW_REG_XCC_ID); dir = xcd&1, batch-group bg = xcd>>2..
// (bg = xcd>>1); slot via per-XCD atomicAdd -> unit range u0 = slot*16.
// All h + flag traffic for a group touches ONLY that XCD's WGs -> lines stay
// in the XCD-private L2 (coherent there). sc0 loads bypass L1, hit local L2
// (~200cy RTT vs ~2k cy for agent-scope coherence-point ops).
// Protocol (proven in R0 at device scope): store h -> vmcnt(0) -> barrier ->
// flag=t+1; consumer polls 32 flags >= t then reads h. Ping-pong buffers;
// flag t+2 implies reads of h(t) done, so overwrite at t+2 is safe.
// Watchdog bounds all spins (placement failure -> visible wrong answer).
__global__ __launch_bounds__(256, 1) void lstm_scan_kernel(
    const unsigned short* __restrict__ Axt,
    const unsigned short* __restrict__ Wt,
    const float* __restrict__ bias_f, const float* __restrict__ bias_b,
    const unsigned long long* __restrict__ maskbits,
    unsigned short* __restrict__ hline,   // [8 grp][2 buf][16 b][512 u] bf16
    unsigned int* __restrict__ flags,     // [8 grp][64]
    unsigned int* __restrict__ slotctr,   // [8]
    float* __restrict__ out) {
  __shared__ alignas(16) short lds_b[4 * 32 * 64 * 8];   // 128 KiB
  __shared__ int sh_xcd, sh_slot;

  const int tid  = threadIdx.x;
  const int lane = tid & 63;
  const int wv   = tid >> 6;

  if (tid == 0) {
    unsigned x;
    asm volatile("s_getreg_b32 %0, hwreg(HW_REG_XCC_ID)" : "=s"(x));
    x &= 7u;
    sh_xcd  = (int)x;
    sh_slot = (int)(atomicAdd(&slotctr[x], 1u) & 31u);
  }
  __syncthreads();
  const int xcd  = sh_xcd;
  const int slot = sh_slot;
  const int dir  = xcd & 1;
  const int bg   = xcd >> 1;           // batch group: batches [bg*16, bg*16+16)
  const int u0   = slot * 16;          // unit range [u0, u0+16)

  // LDS B-frags: item (nt,ks,ln) -> Wcat[k = ks*32+(ln>>4)*8+j]
  //   [col cl = nt*16 + (ln&15)], cl = uo*4 + g, global col = g*512 + u0 + uo.
  const unsigned short* wsrc = Wt + (size_t)dir * 2048 * 1024;
  for (int item = tid; item < 4 * 32 * 64; item += 256) {
    int nt = item >> 11;
    int ks = (item >> 6) & 31;
    int ln = item & 63;
    int cl = nt * 16 + (ln & 15);
    int Cg = (cl & 3) * U_SZ + u0 + (cl >> 2);
    int kbase = ks * 32 + ((ln >> 4) << 3);
    short8 v = *(const short8*)(wsrc + (size_t)Cg * 1024 + kbase);
    *(short8*)(&lds_b[item * 8]) = v;
  }
  __syncthreads();

  const int gam = lane & 3;            // gate owned pre-transpose
  const int du4 = (lane & 15) >> 2;
  const int u   = u0 + wv * 4 + du4;   // this lane's unit
  const int bl  = ((lane >> 4) << 2) + gam;   // this lane's local batch
  const int bglob = bg * 16 + bl;
  const float* bias = dir ? bias_b : bias_f;
  const float bzl = bias[gam * U_SZ + u];

  float c_st = 0.f, h_st = 0.f;

  unsigned short* hgrp = hline + (size_t)xcd * (2 * 16 * 512);
  unsigned int* fgrp = flags + xcd * 64;
  const unsigned int* fp = fgrp + (lane & 31);  // poll address (fixed)

  const int arow = lane & 15;          // A-frag row (local batch)
  const int kq   = (lane >> 4) << 3;   // A-frag k sub-offset

  for (int t = 0; t < S_LEN; ++t) {
    const int sx = dir ? (S_LEN - 1 - t) : t;

    // x A-frags (plain cached loads; identical across iterations)
    const unsigned short* xs = Axt + (size_t)sx * B_SZ * D_IN +
                               (size_t)(bg * 16 + arow) * D_IN + kq;
    short8 xa[16];
#pragma unroll
    for (int ks = 0; ks < 16; ++ks) xa[ks] = *(const short8*)(xs + ks * 32);

    const unsigned long long mb = maskbits[sx];

    floatx4 acc = {0.f, 0.f, 0.f, 0.f};
    // x @ W — independent of h, runs before the poll
#pragma unroll
    for (int ks = 0; ks < 16; ++ks) {
      short8 b = *(const short8*)(&lds_b[((wv * 32 + ks) * 64 + lane) * 8]);
      acc = __builtin_amdgcn_mfma_f32_16x16x32_bf16(xa[ks], b, acc, 0, 0, 0);
    }

    // poll the 32 in-XCD flags (sc0 -> local L2)
    if (t > 0) {
      int spins = 0;
      while (true) {
        unsigned fv;
        asm volatile("global_load_dword %0, %1, off sc0\n\t"
                     "s_waitcnt vmcnt(0)"
                     : "=v"(fv) : "v"(fp) : "memory");
        if (__ballot(fv >= (unsigned)t) == ~0ull) break;
        if (++spins > SPIN_CAP) break;               // watchdog
        __builtin_amdgcn_s_sleep(1);
      }
    }

    // h A-frags from XCD-local L2 (sc0); 16B x 16 with literal offsets
    const unsigned short* hr = hgrp + (size_t)((t + 1) & 1) * (16 * 512) +
                               (size_t)arow * 512 + kq;
    HU hq[16];
    HLOAD(0, 0);    HLOAD(1, 64);   HLOAD(2, 128);  HLOAD(3, 192);
    HLOAD(4, 256);  HLOAD(5, 320);  HLOAD(6, 384);  HLOAD(7, 448);
    HLOAD(8, 512);  HLOAD(9, 576);  HLOAD(10, 640); HLOAD(11, 704);
    HLOAD(12, 768); HLOAD(13, 832); HLOAD(14, 896); HLOAD(15, 960);
    asm volatile("s_waitcnt vmcnt(0)" ::: "memory");
    __builtin_amdgcn_sched_barrier(0);

    // h @ R
#pragma unroll
    for (int ks = 0; ks < 16; ++ks) {
      short8 b = *(const short8*)(&lds_b[((wv * 32 + 16 + ks) * 64 + lane) * 8]);
      acc = __builtin_amdgcn_mfma_f32_16x16x32_bf16(hq[ks].s, b, acc, 0, 0, 0);
    }

    // bias + 4x4 transpose within each 4-lane gate quad:
    // pre: lane gam holds z[batch r][gate gam], r=0..3 (+ its gate bias)
    // post: lane gam holds a_t = z[batch bl][gate t], t=0..3
    float a0 = acc[0] + bzl, a1 = acc[1] + bzl,
          a2 = acc[2] + bzl, a3 = acc[3] + bzl;
    {
      float s_, r_;
      s_ = (gam & 1) ? a0 : a1; r_ = __shfl_xor(s_, 1, 64);
      if (gam & 1) a0 = r_; else a1 = r_;
      s_ = (gam & 1) ? a2 : a3; r_ = __shfl_xor(s_, 1, 64);
      if (gam & 1) a2 = r_; else a3 = r_;
      s_ = (gam & 2) ? a0 : a2; r_ = __shfl_xor(s_, 2, 64);
      if (gam & 2) a0 = r_; else a2 = r_;
      s_ = (gam & 2) ? a1 : a3; r_ = __shfl_xor(s_, 2, 64);
      if (gam & 2) a1 = r_; else a3 = r_;
    }
    // a0=zi a1=zf a2=zg a3=zo for (batch bl, unit u)
    {
      float cn = fsig(a1) * c_st + fsig(a0) * ftanh(a2);
      float hn = fsig(a3) * ftanh(cn);
      bool m = (mb >> bglob) & 1ull;
      c_st = m ? cn : c_st;
      h_st = m ? hn : h_st;
    }

    // publish h: one bf16 per lane into XCD-local buffer (sc0 write-through)
    {
      unsigned short* hw = hgrp + (size_t)(t & 1) * (16 * 512) +
                           (size_t)bl * 512 + u;
      unsigned hv = (unsigned)f2bf(h_st);
      asm volatile("global_store_short %0, %1, off sc0"
                   :: "v"(hw), "v"(hv) : "memory");
    }
    asm volatile("s_waitcnt vmcnt(0)" ::: "memory");
    __syncthreads();                    // all waves' h stores drained
    if (tid == 0) {
      unsigned fv = (unsigned)(t + 1);
      unsigned int* fs = fgrp + slot;
      asm volatile("global_store_dword %0, %1, off sc0"
                   :: "v"(fs), "v"(fv) : "memory");
    }

    // output writes — off the ring's critical path
    __builtin_nontemporal_store(
        h_st, out + ((size_t)bglob * S_LEN + sx) * 1024 + dir * U_SZ + u);
    if (t == S_LEN - 1) {               // final h, c (post-mask carries)
      float* fin = out + (size_t)B_SZ * S_LEN * 1024 +
                   (size_t)dir * 2 * B_SZ * U_SZ;
      fin[bglob * U_SZ + u] = h_st;
      fin[B_SZ * U_SZ + bglob * U_SZ + u] = c_st;
    }
  }
}

extern "C" void kernel_launch(void* const* d_in, const int* in_sizes, int n_in,
                              void* d_out, int out_size, void* d_ws, size_t ws_size,
                              hipStream_t stream) {
  const float* inputs    = (const float*)d_in[0];
  const void*  mask      = d_in[1];
  const float* kernel_f  = (const float*)d_in[2];
  const float* rkernel_f = (const float*)d_in[3];
  const float* bias_f    = (const float*)d_in[4];
  const float* kernel_b  = (const float*)d_in[5];
  const float* rkernel_b = (const float*)d_in[6];
  const float* bias_b    = (const float*)d_in[7];
  float* out = (float*)d_out;

  char* ws = (char*)d_ws;
  unsigned short* Axt = (unsigned short*)ws;                    // 67,108,864 B
  size_t off = (size_t)S_LEN * B_SZ * D_IN * 2;
  unsigned short* Wt = (unsigned short*)(ws + off);             //  8,388,608 B
  size_t off2 = off + (size_t)2 * 2048 * 1024 * 2;
  unsigned short* hline = (unsigned short*)(ws + off2);         //    262,144 B
  unsigned int* flags   = (unsigned int*)(ws + off2 + 262144);  //      2,048 B
  unsigned int* slotctr = (unsigned int*)(ws + off2 + 262144 + 2048);  // 256 B
  unsigned long long* maskbits =
      (unsigned long long*)(ws + off2 + 262144 + 2048 + 256);   //      8,192 B

  hipMemsetAsync(hline, 0, 262144 + 2048 + 256, stream);  // h, flags, slots
  maskpack_kernel<<<4, 256, 0, stream>>>((const unsigned int*)mask, maskbits);
  xprep_kernel<<<S_LEN * B_SZ, 128, 0, stream>>>(inputs, Axt);
  wprep_kernel<<<4096, 256, 0, stream>>>(kernel_f, rkernel_f,
                                         kernel_b, rkernel_b, Wt);
  lstm_scan_kernel<<<256, 256, 0, stream>>>(Axt, Wt, bias_f, bias_b,
                                            maskbits, hline, flags, slotctr,
                                            out);
}